// Round 1
// baseline (412.207 us; speedup 1.0000x reference)
//
#include <hip/hip_runtime.h>

// Element-wise: y = min(((x+1)*0.75)^2, 10.0f), fp32 in/out, 8192*8192 elems.
// Memory-bound; float4 vectorized, one float4 per thread.

__global__ __launch_bounds__(256) void ew_kernel(const float4* __restrict__ x,
                                                 float4* __restrict__ out,
                                                 int n4) {
    int i = blockIdx.x * blockDim.x + threadIdx.x;
    if (i < n4) {
        float4 v = x[i];
        float4 r;
        float t;
        t = (v.x + 1.0f) * 0.75f; t = t * t; r.x = fminf(t, 10.0f);
        t = (v.y + 1.0f) * 0.75f; t = t * t; r.y = fminf(t, 10.0f);
        t = (v.z + 1.0f) * 0.75f; t = t * t; r.z = fminf(t, 10.0f);
        t = (v.w + 1.0f) * 0.75f; t = t * t; r.w = fminf(t, 10.0f);
        out[i] = r;
    }
}

extern "C" void kernel_launch(void* const* d_in, const int* in_sizes, int n_in,
                              void* d_out, int out_size, void* d_ws, size_t ws_size,
                              hipStream_t stream) {
    const float* x = (const float*)d_in[0];
    float* out = (float*)d_out;
    int n = in_sizes[0];          // 8192*8192 = 67108864, divisible by 4
    int n4 = n / 4;
    int block = 256;
    int grid = (n4 + block - 1) / block;
    ew_kernel<<<grid, block, 0, stream>>>((const float4*)x, (float4*)out, n4);
}